// Round 11
// baseline (32.269 us; speedup 1.0000x reference)
//
#include <hip/hip_runtime.h>
#include <math.h>

#define NODES   100000
#define DIM     128
#define NEDGES  1600000          // 4 * 400000
#define NQUADS  (NEDGES / 4)     // 400000; == 1563 blocks * 256 - pad
#define NGROUPS (NODES / 8)      // 12500 32-lane groups, 8 nodes each

#define LOG2E 1.44269504088896340736f

// clang-native vector types
typedef int      v4i  __attribute__((ext_vector_type(4)));
typedef uint32_t v4u  __attribute__((ext_vector_type(4)));
typedef float    v4f  __attribute__((ext_vector_type(4)));
typedef _Float16 h2   __attribute__((ext_vector_type(2)));

__device__ __forceinline__ float fast_sigmoid(float x) {
    return __builtin_amdgcn_rcpf(1.0f + __builtin_amdgcn_exp2f(-x * LOG2E));
}

__device__ __forceinline__ float dot4(v4f a, v4f b) {
    return a.x * b.x + a.y * b.y + a.z * b.z + a.w * b.w;
}

// Phase 1: p[n] = pack_f16x2( h[n].Wu , h[n].Wv + bias ).  (R8 structure:
// 32 lanes/node, 8 nodes/thread, ILP=8; measured at the L3-BW floor ~3 us.)
__global__ __launch_bounds__(256) void node_proj_kernel(
    const float* __restrict__ h,
    const float* __restrict__ W,      // 256 floats: Wu | Wv
    const float* __restrict__ bias_ptr,
    uint32_t* __restrict__ p)
{
    const int tid  = blockIdx.x * 256 + threadIdx.x;
    const int lane = tid & 31;
    const int grp  = tid >> 5;
    if (grp >= NGROUPS) return;
    const int n0 = grp * 8;

    const v4f wu = *reinterpret_cast<const v4f*>(W + lane * 4);
    const v4f wv = *reinterpret_cast<const v4f*>(W + DIM + lane * 4);
    const float b = bias_ptr[0];

    const float* hb = h + (size_t)n0 * DIM + lane * 4;
    v4f hr[8];
    #pragma unroll
    for (int j = 0; j < 8; ++j)
        hr[j] = *reinterpret_cast<const v4f*>(hb + j * DIM);

    float su[8], sv[8];
    #pragma unroll
    for (int j = 0; j < 8; ++j) {
        su[j] = dot4(hr[j], wu);
        sv[j] = dot4(hr[j], wv);
    }

    #pragma unroll
    for (int off = 16; off >= 1; off >>= 1) {
        #pragma unroll
        for (int j = 0; j < 8; ++j) {
            su[j] += __shfl_xor(su[j], off);
            sv[j] += __shfl_xor(sv[j], off);
        }
    }

    if (lane == 0) {
        uint32_t w[8];
        #pragma unroll
        for (int j = 0; j < 8; ++j)
            w[j] = __builtin_bit_cast(uint32_t,
                       __builtin_amdgcn_cvt_pkrtz(su[j], sv[j] + b));
        v4u w0 = { w[0], w[1], w[2], w[3] };
        v4u w1 = { w[4], w[5], w[6], w[7] };
        *reinterpret_cast<v4u*>(p + n0)     = w0;
        *reinterpret_cast<v4u*>(p + n0 + 4) = w1;
    }
}

// Phase 2: out[e] = sigmoid( f16lo(p[src[e]]) + f16hi(p[dst[e]]) ).
// 4 edges/thread (R9-measured best gather structure), 8 gathers issued
// up front, ALL table gathers nontemporal: nearly every gather L1-misses
// anyway (400 KB table vs 32 KB L1), so skip line retention/allocation
// work and reduce L2->L1 fill traffic. src/dst loads stay cached
// (L3-resident across replays).
__global__ __launch_bounds__(256) void edge_score_kernel(
    const int*      __restrict__ src,
    const int*      __restrict__ dst,
    const uint32_t* __restrict__ p,
    float* __restrict__ out)
{
    const int i = blockIdx.x * 256 + threadIdx.x;
    if (i >= NQUADS) return;

    v4i s4 = reinterpret_cast<const v4i*>(src)[i];
    v4i d4 = reinterpret_cast<const v4i*>(dst)[i];

    // 8 independent NT gathers in flight.
    uint32_t ws0 = __builtin_nontemporal_load(p + s4.x);
    uint32_t wd0 = __builtin_nontemporal_load(p + d4.x);
    uint32_t ws1 = __builtin_nontemporal_load(p + s4.y);
    uint32_t wd1 = __builtin_nontemporal_load(p + d4.y);
    uint32_t ws2 = __builtin_nontemporal_load(p + s4.z);
    uint32_t wd2 = __builtin_nontemporal_load(p + d4.z);
    uint32_t ws3 = __builtin_nontemporal_load(p + s4.w);
    uint32_t wd3 = __builtin_nontemporal_load(p + d4.w);

    v4f r;
    r.x = fast_sigmoid((float)__builtin_bit_cast(h2, ws0).x + (float)__builtin_bit_cast(h2, wd0).y);
    r.y = fast_sigmoid((float)__builtin_bit_cast(h2, ws1).x + (float)__builtin_bit_cast(h2, wd1).y);
    r.z = fast_sigmoid((float)__builtin_bit_cast(h2, ws2).x + (float)__builtin_bit_cast(h2, wd2).y);
    r.w = fast_sigmoid((float)__builtin_bit_cast(h2, ws3).x + (float)__builtin_bit_cast(h2, wd3).y);

    __builtin_nontemporal_store(r, reinterpret_cast<v4f*>(out) + i);
}

extern "C" void kernel_launch(void* const* d_in, const int* in_sizes, int n_in,
                              void* d_out, int out_size, void* d_ws, size_t ws_size,
                              hipStream_t stream) {
    const float* h    = (const float*)d_in[0];
    const int*   src  = (const int*)d_in[1];
    const int*   dst  = (const int*)d_in[2];
    const float* W    = (const float*)d_in[3];   // (1, 256)
    const float* bias = (const float*)d_in[4];   // (1,)
    float* out = (float*)d_out;

    uint32_t* p = (uint32_t*)d_ws;               // NODES packed f16x2 entries (400 KB)

    // Phase 1: 32 lanes/node, 8 nodes/thread -> 400k threads -> 1563 blocks.
    node_proj_kernel<<<(NGROUPS * 32 + 255) / 256, 256, 0, stream>>>(h, W, bias, p);

    // Phase 2: 4 edges/thread -> 400k threads -> 1563 blocks.
    edge_score_kernel<<<(NQUADS + 255) / 256, 256, 0, stream>>>(src, dst, p, out);
}

// Round 12
// 30.967 us; speedup vs baseline: 1.0420x; 1.0420x over previous
//
#include <hip/hip_runtime.h>
#include <math.h>

#define NODES   100000
#define DIM     128
#define NEDGES  1600000          // 4 * 400000
#define NQUADS  (NEDGES / 4)     // 400000
#define NGROUPS (NODES / 8)      // 12500 32-lane groups, 8 nodes each

#define LOG2E 1.44269504088896340736f

// clang-native vector types
typedef int      v4i  __attribute__((ext_vector_type(4)));
typedef uint32_t v4u  __attribute__((ext_vector_type(4)));
typedef float    v4f  __attribute__((ext_vector_type(4)));
typedef _Float16 h2   __attribute__((ext_vector_type(2)));

__device__ __forceinline__ float fast_sigmoid(float x) {
    return __builtin_amdgcn_rcpf(1.0f + __builtin_amdgcn_exp2f(-x * LOG2E));
}

__device__ __forceinline__ float dot4(v4f a, v4f b) {
    return a.x * b.x + a.y * b.y + a.z * b.z + a.w * b.w;
}

// Phase 1: p[n] = pack_f16x2( h[n].Wu , h[n].Wv + bias ).  (R8 structure:
// 32 lanes/node, 8 nodes/thread, ILP=8; measured at the L3-BW floor ~3 us.)
__global__ __launch_bounds__(256) void node_proj_kernel(
    const float* __restrict__ h,
    const float* __restrict__ W,      // 256 floats: Wu | Wv
    const float* __restrict__ bias_ptr,
    uint32_t* __restrict__ p)
{
    const int tid  = blockIdx.x * 256 + threadIdx.x;
    const int lane = tid & 31;
    const int grp  = tid >> 5;
    if (grp >= NGROUPS) return;
    const int n0 = grp * 8;

    const v4f wu = *reinterpret_cast<const v4f*>(W + lane * 4);
    const v4f wv = *reinterpret_cast<const v4f*>(W + DIM + lane * 4);
    const float b = bias_ptr[0];

    const float* hb = h + (size_t)n0 * DIM + lane * 4;
    v4f hr[8];
    #pragma unroll
    for (int j = 0; j < 8; ++j)
        hr[j] = *reinterpret_cast<const v4f*>(hb + j * DIM);

    float su[8], sv[8];
    #pragma unroll
    for (int j = 0; j < 8; ++j) {
        su[j] = dot4(hr[j], wu);
        sv[j] = dot4(hr[j], wv);
    }

    #pragma unroll
    for (int off = 16; off >= 1; off >>= 1) {
        #pragma unroll
        for (int j = 0; j < 8; ++j) {
            su[j] += __shfl_xor(su[j], off);
            sv[j] += __shfl_xor(sv[j], off);
        }
    }

    if (lane == 0) {
        uint32_t w[8];
        #pragma unroll
        for (int j = 0; j < 8; ++j)
            w[j] = __builtin_bit_cast(uint32_t,
                       __builtin_amdgcn_cvt_pkrtz(su[j], sv[j] + b));
        v4u w0 = { w[0], w[1], w[2], w[3] };
        v4u w1 = { w[4], w[5], w[6], w[7] };
        *reinterpret_cast<v4u*>(p + n0)     = w0;
        *reinterpret_cast<v4u*>(p + n0 + 4) = w1;
    }
}

// Phase 2: out[e] = sigmoid( f16lo(p[src[e]]) + f16hi(p[dst[e]]) ).
// 4 edges/thread, 8 CACHED gathers in flight (L1 retention of table lines is
// worth ~2.7 us — R11 lesson). NT is applied ONLY to the pure streams
// (src/dst index loads, out stores) so they don't evict table lines from L1.
// Core is MSHR x L2-latency bound (~13 us); TLP: 24 waves/CU keeps MSHRs full.
__global__ __launch_bounds__(256) void edge_score_kernel(
    const int*      __restrict__ src,
    const int*      __restrict__ dst,
    const uint32_t* __restrict__ p,
    float* __restrict__ out)
{
    const int i = blockIdx.x * 256 + threadIdx.x;
    if (i >= NQUADS) return;

    v4i s4 = __builtin_nontemporal_load(reinterpret_cast<const v4i*>(src) + i);
    v4i d4 = __builtin_nontemporal_load(reinterpret_cast<const v4i*>(dst) + i);

    // 8 independent cached gathers in flight.
    uint32_t ws0 = p[s4.x], wd0 = p[d4.x];
    uint32_t ws1 = p[s4.y], wd1 = p[d4.y];
    uint32_t ws2 = p[s4.z], wd2 = p[d4.z];
    uint32_t ws3 = p[s4.w], wd3 = p[d4.w];

    v4f r;
    r.x = fast_sigmoid((float)__builtin_bit_cast(h2, ws0).x + (float)__builtin_bit_cast(h2, wd0).y);
    r.y = fast_sigmoid((float)__builtin_bit_cast(h2, ws1).x + (float)__builtin_bit_cast(h2, wd1).y);
    r.z = fast_sigmoid((float)__builtin_bit_cast(h2, ws2).x + (float)__builtin_bit_cast(h2, wd2).y);
    r.w = fast_sigmoid((float)__builtin_bit_cast(h2, ws3).x + (float)__builtin_bit_cast(h2, wd3).y);

    __builtin_nontemporal_store(r, reinterpret_cast<v4f*>(out) + i);
}

extern "C" void kernel_launch(void* const* d_in, const int* in_sizes, int n_in,
                              void* d_out, int out_size, void* d_ws, size_t ws_size,
                              hipStream_t stream) {
    const float* h    = (const float*)d_in[0];
    const int*   src  = (const int*)d_in[1];
    const int*   dst  = (const int*)d_in[2];
    const float* W    = (const float*)d_in[3];   // (1, 256)
    const float* bias = (const float*)d_in[4];   // (1,)
    float* out = (float*)d_out;

    uint32_t* p = (uint32_t*)d_ws;               // NODES packed f16x2 entries (400 KB)

    // Phase 1: 32 lanes/node, 8 nodes/thread -> 400k threads -> 1563 blocks.
    node_proj_kernel<<<(NGROUPS * 32 + 255) / 256, 256, 0, stream>>>(h, W, bias, p);

    // Phase 2: 4 edges/thread -> 400k threads -> 1563 blocks.
    edge_score_kernel<<<(NQUADS + 255) / 256, 256, 0, stream>>>(src, dst, p, out);
}

// Round 13
// 29.629 us; speedup vs baseline: 1.0891x; 1.0452x over previous
//
#include <hip/hip_runtime.h>
#include <math.h>

#define NODES   100000
#define DIM     128
#define NEDGES  1600000          // 4 * 400000; == 6250 * 256 exactly
#define NGROUPS (NODES / 8)      // 12500 32-lane groups, 8 nodes each

#define LOG2E 1.44269504088896340736f

// clang-native vector types
typedef int      v4i  __attribute__((ext_vector_type(4)));
typedef uint32_t v4u  __attribute__((ext_vector_type(4)));
typedef float    v4f  __attribute__((ext_vector_type(4)));
typedef _Float16 h2   __attribute__((ext_vector_type(2)));

__device__ __forceinline__ float fast_sigmoid(float x) {
    return __builtin_amdgcn_rcpf(1.0f + __builtin_amdgcn_exp2f(-x * LOG2E));
}

__device__ __forceinline__ float dot4(v4f a, v4f b) {
    return a.x * b.x + a.y * b.y + a.z * b.z + a.w * b.w;
}

// Phase 1: p[n] = pack_f16x2( h[n].Wu , h[n].Wv + bias ).
// 32 lanes/node (per-instruction contiguous 512B/half-wave), 8 nodes/thread
// (ILP=8), W slice in registers. Measured at the L3-BW floor (~3 us marginal).
// Packed-f16 table (400 KB) halves phase-2 footprint vs 2x f32: -2.1 us (R10).
// f16 RTZ error ~4e-3 per term, sigmoid slope <= 0.25 -> output err ~2e-3,
// measured absmax 0.0039 << 2e-2 threshold.
__global__ __launch_bounds__(256) void node_proj_kernel(
    const float* __restrict__ h,
    const float* __restrict__ W,      // 256 floats: Wu | Wv
    const float* __restrict__ bias_ptr,
    uint32_t* __restrict__ p)
{
    const int tid  = blockIdx.x * 256 + threadIdx.x;
    const int lane = tid & 31;
    const int grp  = tid >> 5;
    if (grp >= NGROUPS) return;
    const int n0 = grp * 8;

    const v4f wu = *reinterpret_cast<const v4f*>(W + lane * 4);
    const v4f wv = *reinterpret_cast<const v4f*>(W + DIM + lane * 4);
    const float b = bias_ptr[0];

    const float* hb = h + (size_t)n0 * DIM + lane * 4;
    v4f hr[8];
    #pragma unroll
    for (int j = 0; j < 8; ++j)
        hr[j] = *reinterpret_cast<const v4f*>(hb + j * DIM);

    float su[8], sv[8];
    #pragma unroll
    for (int j = 0; j < 8; ++j) {
        su[j] = dot4(hr[j], wu);
        sv[j] = dot4(hr[j], wv);
    }

    #pragma unroll
    for (int off = 16; off >= 1; off >>= 1) {
        #pragma unroll
        for (int j = 0; j < 8; ++j) {
            su[j] += __shfl_xor(su[j], off);
            sv[j] += __shfl_xor(sv[j], off);
        }
    }

    if (lane == 0) {
        uint32_t w[8];
        #pragma unroll
        for (int j = 0; j < 8; ++j)
            w[j] = __builtin_bit_cast(uint32_t,
                       __builtin_amdgcn_cvt_pkrtz(su[j], sv[j] + b));
        v4u w0 = { w[0], w[1], w[2], w[3] };
        v4u w1 = { w[4], w[5], w[6], w[7] };
        *reinterpret_cast<v4u*>(p + n0)     = w0;
        *reinterpret_cast<v4u*>(p + n0 + 4) = w1;
    }
}

// Phase 2: out[e] = sigmoid( f16lo(p[src[e]]) + f16hi(p[dst[e]]) ).
// 1 edge/thread: max TLP is the only lever that matters — the core is
// MSHR x L2-latency bound on 3.2M irreducible random 4B gathers (R9
// instrumentation: ~13 us steady-state; ALU/ILP/NT all null or negative,
// R5/R11/R12 ledger). Gathers CACHED (L1+L2 retention worth ~2.7 us vs NT).
// Only the out store is nontemporal (pure stream).
__global__ __launch_bounds__(256) void edge_score_kernel(
    const int*      __restrict__ src,
    const int*      __restrict__ dst,
    const uint32_t* __restrict__ p,
    float* __restrict__ out)
{
    const int i = blockIdx.x * 256 + threadIdx.x;   // grid exact: 6250*256 == NEDGES

    const int s = src[i];
    const int d = dst[i];

    const uint32_t ws = p[s];
    const uint32_t wd = p[d];

    const float a = (float)__builtin_bit_cast(h2, ws).x;   // pu[s]
    const float c = (float)__builtin_bit_cast(h2, wd).y;   // pv[d] (+bias)

    __builtin_nontemporal_store(fast_sigmoid(a + c), out + i);
}

extern "C" void kernel_launch(void* const* d_in, const int* in_sizes, int n_in,
                              void* d_out, int out_size, void* d_ws, size_t ws_size,
                              hipStream_t stream) {
    const float* h    = (const float*)d_in[0];
    const int*   src  = (const int*)d_in[1];
    const int*   dst  = (const int*)d_in[2];
    const float* W    = (const float*)d_in[3];   // (1, 256)
    const float* bias = (const float*)d_in[4];   // (1,)
    float* out = (float*)d_out;

    uint32_t* p = (uint32_t*)d_ws;               // NODES packed f16x2 entries (400 KB)

    // Phase 1: 32 lanes/node, 8 nodes/thread -> 400k threads -> 1563 blocks.
    node_proj_kernel<<<(NGROUPS * 32 + 255) / 256, 256, 0, stream>>>(h, W, bias, p);

    // Phase 2: 1 edge/thread -> 1.6M threads -> 6250 blocks (exact).
    edge_score_kernel<<<NEDGES / 256, 256, 0, stream>>>(src, dst, p, out);
}